// Round 3
// baseline (1088.352 us; speedup 1.0000x reference)
//
#include <hip/hip_runtime.h>
#include <stdint.h>
#include <stddef.h>

// z = x[32768,512] @ W[2048,512]^T + B; per-row instance-norm over 2048;
// out = (z_norm + y) * y.  f32 I/O, bf16 MFMA (32x32x16) internally.
//
// Persistent: 256 blocks (1/CU), 8 waves, each block does 4 generations of
// BM=32 rows. Wave w owns cols [w*256, w*256+256) as 8 frags of 32 cols.
// Epilogue stores directly from the 32x32 C-frag layout: each store instr
// covers 2 full 128B lines -> exact HBM traffic, no LDS transpose, no
// trailing barrier (epilogue(g) overlaps K(g+1) across waves).

typedef float  f32x16_t __attribute__((ext_vector_type(16)));
typedef short  short8_t __attribute__((ext_vector_type(8)));

#define BATCH   32768
#define INF     512
#define OUTF    2048
#define BM      32
#define GENS    4
#define ROWS_PER_BLK (BM * GENS)         // 128
#define NBLK    (BATCH / ROWS_PER_BLK)   // 256
#define THREADS 512
#define WB_BYTES (OUTF * INF * 2)        // 2 MB bf16 W

// LDS layout
#define A_OFF(p)   ((p) * 32768)         // 2 x 32 KB A tiles (bf16)
#define ST_OFF(p)  (65536 + (p) * 2048)  // 2 x [8 waves][32 rows][2] f32
#define RS_OFF(p)  (69632 + (p) * 256)   // 2 x [32][2] f32 (mean, rstd)
#define SMEM_BYTES 70144

__device__ __forceinline__ unsigned short f2bf(float f) {
    unsigned int u = __builtin_bit_cast(unsigned int, f);
    u += 0x7FFFu + ((u >> 16) & 1u);     // round-to-nearest-even
    return (unsigned short)(u >> 16);
}

__device__ __forceinline__ short8_t pack8(float4 a, float4 b) {
    short8_t v;
    v[0] = (short)f2bf(a.x); v[1] = (short)f2bf(a.y);
    v[2] = (short)f2bf(a.z); v[3] = (short)f2bf(a.w);
    v[4] = (short)f2bf(b.x); v[5] = (short)f2bf(b.y);
    v[6] = (short)f2bf(b.z); v[7] = (short)f2bf(b.w);
    return v;
}

// Prepass: W f32 [2048,512] -> Wb bf16, frag-major for 32x32x16:
// elem(s, col, half, j) at s*32768 + col*16 + half*8 + j   (k = s*16 + half*8 + j)
// Thread id = col*64 + k8 (k8 = k/8): reads coalesced (wave = one col, 2 KB).
__global__ __launch_bounds__(256) void conv_w_kernel(const float* __restrict__ W,
                                                     unsigned short* __restrict__ Wb) {
    int id  = blockIdx.x * 256 + threadIdx.x;   // col*64 + k8
    int col = id >> 6;
    int k8  = id & 63;
    const float* src = W + (size_t)col * INF + k8 * 8;
    float4 a = *(const float4*)src;
    float4 b = *(const float4*)(src + 4);
    *(short8_t*)(Wb + (size_t)(k8 >> 1) * 32768 + col * 16 + (k8 & 1) * 8) = pack8(a, b);
}

// A-frag (32x32x16): lane l -> A[row = l&31][k = s*16 + (l>>5)*8 + j], j=0..7
// A LDS addr(s,row,half) = s*1024 + row*32 + half*16  (bytes)
// C-frag: col = lane&31, row = (q&3) + 8*(q>>2) + 4*(lane>>5), q=0..15
template <bool USE_WB>
__global__ __launch_bounds__(THREADS, 2) void fused_kernel(
    const float* __restrict__ x, const float* __restrict__ y,
    const float* __restrict__ W, const float* __restrict__ Bias,
    const unsigned short* __restrict__ Wb, float* __restrict__ out) {

    __shared__ __align__(16) char smem[SMEM_BYTES];

    const int t    = threadIdx.x;
    const int w    = t >> 6;
    const int l    = t & 63;
    const int c31  = l & 31;
    const int half = l >> 5;
    const int m_base = blockIdx.x * ROWS_PER_BLK;

    // bias per lane: one value per 32-col frag
    float biasv[8];
    #pragma unroll
    for (int ni = 0; ni < 8; ++ni)
        biasv[ni] = Bias[w * 256 + ni * 32 + c31];

    // W access bases
    const char* wbase = nullptr;     // + s*65536 + ni*1024 (bytes)
    const float* wf   = nullptr;     // + ni*32*INF + s*16  (elems)
    if (USE_WB) wbase = (const char*)Wb + (size_t)(w * 256 + c31) * 32 + half * 16;
    else        wf    = W + (size_t)(w * 256 + c31) * INF + half * 8;

    // ---- prologue: stage gen 0 into A[0] (wave w reads rows w, w+8, w+16, w+24) ----
    {
        char* Ab = smem + A_OFF(0);
        const float* xs = x + (size_t)(m_base + w) * INF + l * 8;
        char* dst = Ab + (l >> 1) * 1024 + w * 32 + (l & 1) * 16;
        #pragma unroll
        for (int i = 0; i < 4; ++i) {   // row = w + 8i, k8 = l
            float4 a = *(const float4*)(xs + i * 8 * INF);
            float4 b = *(const float4*)(xs + i * 8 * INF + 4);
            *(short8_t*)(dst + i * 256) = pack8(a, b);
        }
    }
    __syncthreads();

    for (int g = 0; g < GENS; ++g) {
        const int par = g & 1;
        const char* Acur    = smem + A_OFF(par);
        char*       Anxt    = smem + A_OFF(par ^ 1);
        float*      stats   = (float*)(smem + ST_OFF(par));
        float*      rowstat = (float*)(smem + RS_OFF(par));
        const bool  stage_next = (g + 1 < GENS);

        f32x16_t acc[8];
        #pragma unroll
        for (int ni = 0; ni < 8; ++ni)
            acc[ni] = (f32x16_t)(0.0f);

        // early-issue next-gen x loads (land during this K-loop)
        float4 xa0, xb0, xa1, xb1, xa2, xb2, xa3, xb3;
        const float* xs = x + (size_t)(m_base + (g + 1) * BM + w) * INF + l * 8;
        if (stage_next) {
            xa0 = *(const float4*)(xs);            xb0 = *(const float4*)(xs + 4);
            xa1 = *(const float4*)(xs + 8 * INF);  xb1 = *(const float4*)(xs + 8 * INF + 4);
            xa2 = *(const float4*)(xs + 16 * INF); xb2 = *(const float4*)(xs + 16 * INF + 4);
            xa3 = *(const float4*)(xs + 24 * INF); xb3 = *(const float4*)(xs + 24 * INF + 4);
        }
        char* wdst = Anxt + (l >> 1) * 1024 + w * 32 + (l & 1) * 16;   // + i*256

        const char* aptr = Acur + c31 * 32 + half * 16;                // + s*1024

        // ---- K loop: 32 steps of K=16; W streamed from L2; one staging
        //      ds_write per 8 steps ----
        #pragma unroll
        for (int sc = 0; sc < 4; ++sc) {
            #pragma unroll
            for (int si = 0; si < 8; ++si) {
                const int s = sc * 8 + si;
                short8_t afrag = *(const short8_t*)(aptr + s * 1024);
                #pragma unroll
                for (int ni = 0; ni < 8; ++ni) {
                    short8_t bfr;
                    if (USE_WB) {
                        bfr = *(const short8_t*)(wbase + (size_t)s * 65536 + ni * 1024);
                    } else {
                        const float* p = wf + (size_t)ni * 32 * INF + s * 16;
                        bfr = pack8(*(const float4*)p, *(const float4*)(p + 4));
                    }
                    acc[ni] = __builtin_amdgcn_mfma_f32_32x32x16_bf16(afrag, bfr, acc[ni], 0, 0, 0);
                }
            }
            if (stage_next) {
                if (sc == 0) *(short8_t*)(wdst)       = pack8(xa0, xb0);
                if (sc == 1) *(short8_t*)(wdst + 256) = pack8(xa1, xb1);
                if (sc == 2) *(short8_t*)(wdst + 512) = pack8(xa2, xb2);
                if (sc == 3) *(short8_t*)(wdst + 768) = pack8(xa3, xb3);
            }
        }

        // ---- bias ----
        #pragma unroll
        for (int ni = 0; ni < 8; ++ni)
            #pragma unroll
            for (int q = 0; q < 16; ++q)
                acc[ni][q] += biasv[ni];

        // ---- per-row stats: lane partial over 8 frags, 32-lane xor reduce ----
        #pragma unroll
        for (int q = 0; q < 16; ++q) {
            float s1 = 0.f, s2 = 0.f;
            #pragma unroll
            for (int ni = 0; ni < 8; ++ni) {
                float v = acc[ni][q];
                s1 += v; s2 += v * v;
            }
            #pragma unroll
            for (int d = 1; d < 32; d <<= 1) {
                s1 += __shfl_xor(s1, d);
                s2 += __shfl_xor(s2, d);
            }
            if (c31 == 0) {
                int r = 4 * half + (q & 3) + 8 * (q >> 2);
                stats[(w * 32 + r) * 2]     = s1;
                stats[(w * 32 + r) * 2 + 1] = s2;
            }
        }
        __syncthreads();                 // stats in; A(g+1) fully staged

        if (t < 32) {
            float s1 = 0.f, s2 = 0.f;
            #pragma unroll
            for (int wi = 0; wi < 8; ++wi) {
                s1 += stats[(wi * 32 + t) * 2];
                s2 += stats[(wi * 32 + t) * 2 + 1];
            }
            float mean = s1 * (1.0f / OUTF);
            float var  = s2 * (1.0f / OUTF) - mean * mean;
            rowstat[t * 2]     = mean;
            rowstat[t * 2 + 1] = rsqrtf(var + 1e-5f);
        }
        __syncthreads();                 // rowstat ready

        // ---- epilogue: direct frag stores; every instr = 2 full 128B lines;
        //      no trailing barrier -> flows into K(g+1) ----
        const int m0 = m_base + g * BM;
        const int rbase = 4 * half;
        #pragma unroll
        for (int q = 0; q < 16; ++q) {
            const int r = rbase + (q & 3) + 8 * (q >> 2);
            const float mean = rowstat[r * 2];
            const float rstd = rowstat[r * 2 + 1];
            const size_t off0 = (size_t)(m0 + r) * OUTF + w * 256 + c31;
            #pragma unroll
            for (int ni = 0; ni < 8; ++ni) {
                size_t off = off0 + ni * 32;
                float yv = y[off];
                float zn = (acc[ni][q] - mean) * rstd;
                out[off] = (zn + yv) * yv;
            }
        }
    }
}

extern "C" void kernel_launch(void* const* d_in, const int* in_sizes, int n_in,
                              void* d_out, int out_size, void* d_ws, size_t ws_size,
                              hipStream_t stream) {
    const float* x = (const float*)d_in[0];
    const float* y = (const float*)d_in[1];
    const float* W = (const float*)d_in[2];
    const float* B = (const float*)d_in[3];
    float* out = (float*)d_out;

    if (ws_size >= (size_t)WB_BYTES) {
        unsigned short* Wb = (unsigned short*)d_ws;
        conv_w_kernel<<<512, 256, 0, stream>>>(W, Wb);
        fused_kernel<true><<<NBLK, THREADS, 0, stream>>>(x, y, W, B, Wb, out);
    } else {
        fused_kernel<false><<<NBLK, THREADS, 0, stream>>>(x, y, W, B, nullptr, out);
    }
}

// Round 5
// 1070.261 us; speedup vs baseline: 1.0169x; 1.0169x over previous
//
#include <hip/hip_runtime.h>
#include <stdint.h>
#include <stddef.h>

// z = x[32768,512] @ W[2048,512]^T + B; per-row instance-norm over 2048;
// out = (z_norm + y) * y.  f32 I/O, bf16 MFMA (32x32x16) internally.
//
// Persistent: 256 blocks (1/CU), 8 waves, 4 generations of BM=32 rows.
// Wave w owns cols [w*256, w*256+256) as 8 frags of 32 cols.
// x/y/out accesses are NON-TEMPORAL (nt) so streaming traffic cannot evict
// the L2-resident bf16 W copy (2 MB) — rounds 2/3 showed 4x traffic
// amplification from Wb L2 thrash when the streams mixed.

typedef float  f32x16_t __attribute__((ext_vector_type(16)));
typedef float  f32x4    __attribute__((ext_vector_type(4)));
typedef short  short8_t __attribute__((ext_vector_type(8)));

#define BATCH   32768
#define INF     512
#define OUTF    2048
#define BM      32
#define GENS    4
#define ROWS_PER_BLK (BM * GENS)         // 128
#define NBLK    (BATCH / ROWS_PER_BLK)   // 256
#define THREADS 512
#define WB_BYTES (OUTF * INF * 2)        // 2 MB bf16 W

// LDS layout
#define A_OFF(p)   ((p) * 32768)         // 2 x 32 KB A tiles (bf16)
#define ST_OFF(p)  (65536 + (p) * 2048)  // 2 x [8 waves][32 rows][2] f32
#define RS_OFF(p)  (69632 + (p) * 256)   // 2 x [32][2] f32 (mean, rstd)
#define SMEM_BYTES 70144

__device__ __forceinline__ unsigned short f2bf(float f) {
    unsigned int u = __builtin_bit_cast(unsigned int, f);
    u += 0x7FFFu + ((u >> 16) & 1u);     // round-to-nearest-even
    return (unsigned short)(u >> 16);
}

__device__ __forceinline__ short8_t pack8(f32x4 a, f32x4 b) {
    short8_t v;
    v[0] = (short)f2bf(a[0]); v[1] = (short)f2bf(a[1]);
    v[2] = (short)f2bf(a[2]); v[3] = (short)f2bf(a[3]);
    v[4] = (short)f2bf(b[0]); v[5] = (short)f2bf(b[1]);
    v[6] = (short)f2bf(b[2]); v[7] = (short)f2bf(b[3]);
    return v;
}

__device__ __forceinline__ f32x4 ntload4(const float* p) {
    return __builtin_nontemporal_load((const f32x4*)p);
}

// Prepass: W f32 [2048,512] -> Wb bf16, frag-major for 32x32x16:
// elem(s, col, half, j) at s*32768 + col*16 + half*8 + j   (k = s*16 + half*8 + j)
__global__ __launch_bounds__(256) void conv_w_kernel(const float* __restrict__ W,
                                                     unsigned short* __restrict__ Wb) {
    int id  = blockIdx.x * 256 + threadIdx.x;   // col*64 + k8
    int col = id >> 6;
    int k8  = id & 63;
    const float* src = W + (size_t)col * INF + k8 * 8;
    f32x4 a = *(const f32x4*)src;
    f32x4 b = *(const f32x4*)(src + 4);
    *(short8_t*)(Wb + (size_t)(k8 >> 1) * 32768 + col * 16 + (k8 & 1) * 8) = pack8(a, b);
}

// A-frag (32x32x16): lane l -> A[row = l&31][k = s*16 + (l>>5)*8 + j], j=0..7
// A LDS addr(s,row,half) = s*1024 + row*32 + half*16  (bytes)
// C-frag: col = lane&31, row = (q&3) + 8*(q>>2) + 4*(lane>>5), q=0..15
template <bool USE_WB>
__global__ __launch_bounds__(THREADS, 2) void fused_kernel(
    const float* __restrict__ x, const float* __restrict__ y,
    const float* __restrict__ W, const float* __restrict__ Bias,
    const unsigned short* __restrict__ Wb, float* __restrict__ out) {

    __shared__ __align__(16) char smem[SMEM_BYTES];

    const int t    = threadIdx.x;
    const int w    = t >> 6;
    const int l    = t & 63;
    const int c31  = l & 31;
    const int half = l >> 5;
    const int m_base = blockIdx.x * ROWS_PER_BLK;

    // bias per lane: one value per 32-col frag
    float biasv[8];
    #pragma unroll
    for (int ni = 0; ni < 8; ++ni)
        biasv[ni] = Bias[w * 256 + ni * 32 + c31];

    // W access bases
    const char* wbase = nullptr;     // + s*65536 + ni*1024 (bytes)
    const float* wf   = nullptr;     // + ni*32*INF + s*16  (elems)
    if (USE_WB) wbase = (const char*)Wb + (size_t)(w * 256 + c31) * 32 + half * 16;
    else        wf    = W + (size_t)(w * 256 + c31) * INF + half * 8;

    // ---- prologue: stage gen 0 into A[0] (wave w -> rows w, w+8, w+16, w+24) ----
    {
        char* Ab = smem + A_OFF(0);
        const float* xs = x + (size_t)(m_base + w) * INF + l * 8;
        char* dst = Ab + (l >> 1) * 1024 + w * 32 + (l & 1) * 16;
        #pragma unroll
        for (int i = 0; i < 4; ++i) {   // row = w + 8i, k8 = l
            f32x4 a = ntload4(xs + i * 8 * INF);
            f32x4 b = ntload4(xs + i * 8 * INF + 4);
            *(short8_t*)(dst + i * 256) = pack8(a, b);
        }
    }
    __syncthreads();

    for (int g = 0; g < GENS; ++g) {
        const int par = g & 1;
        const char* Acur    = smem + A_OFF(par);
        char*       Anxt    = smem + A_OFF(par ^ 1);
        float*      stats   = (float*)(smem + ST_OFF(par));
        float*      rowstat = (float*)(smem + RS_OFF(par));
        const bool  stage_next = (g + 1 < GENS);

        f32x16_t acc[8];
        #pragma unroll
        for (int ni = 0; ni < 8; ++ni)
            acc[ni] = (f32x16_t)(0.0f);

        // early-issue next-gen x loads (nt; land during this K-loop)
        f32x4 xa0, xb0, xa1, xb1, xa2, xb2, xa3, xb3;
        const float* xs = x + (size_t)(m_base + (g + 1) * BM + w) * INF + l * 8;
        if (stage_next) {
            xa0 = ntload4(xs);            xb0 = ntload4(xs + 4);
            xa1 = ntload4(xs + 8 * INF);  xb1 = ntload4(xs + 8 * INF + 4);
            xa2 = ntload4(xs + 16 * INF); xb2 = ntload4(xs + 16 * INF + 4);
            xa3 = ntload4(xs + 24 * INF); xb3 = ntload4(xs + 24 * INF + 4);
        }
        char* wdst = Anxt + (l >> 1) * 1024 + w * 32 + (l & 1) * 16;   // + i*256

        const char* aptr = Acur + c31 * 32 + half * 16;                // + s*1024

        // ---- K loop: 32 steps of K=16; W streamed from L2 (regular, cached);
        //      one staging ds_write per 8 steps ----
        #pragma unroll
        for (int sc = 0; sc < 4; ++sc) {
            #pragma unroll
            for (int si = 0; si < 8; ++si) {
                const int s = sc * 8 + si;
                short8_t afrag = *(const short8_t*)(aptr + s * 1024);
                #pragma unroll
                for (int ni = 0; ni < 8; ++ni) {
                    short8_t bfr;
                    if (USE_WB) {
                        bfr = *(const short8_t*)(wbase + (size_t)s * 65536 + ni * 1024);
                    } else {
                        const float* p = wf + (size_t)ni * 32 * INF + s * 16;
                        bfr = pack8(*(const f32x4*)p, *(const f32x4*)(p + 4));
                    }
                    acc[ni] = __builtin_amdgcn_mfma_f32_32x32x16_bf16(afrag, bfr, acc[ni], 0, 0, 0);
                }
            }
            if (stage_next) {
                if (sc == 0) *(short8_t*)(wdst)       = pack8(xa0, xb0);
                if (sc == 1) *(short8_t*)(wdst + 256) = pack8(xa1, xb1);
                if (sc == 2) *(short8_t*)(wdst + 512) = pack8(xa2, xb2);
                if (sc == 3) *(short8_t*)(wdst + 768) = pack8(xa3, xb3);
            }
        }

        // ---- bias ----
        #pragma unroll
        for (int ni = 0; ni < 8; ++ni)
            #pragma unroll
            for (int q = 0; q < 16; ++q)
                acc[ni][q] += biasv[ni];

        // ---- per-row stats: lane partial over 8 frags, 32-lane xor reduce ----
        #pragma unroll
        for (int q = 0; q < 16; ++q) {
            float s1 = 0.f, s2 = 0.f;
            #pragma unroll
            for (int ni = 0; ni < 8; ++ni) {
                float v = acc[ni][q];
                s1 += v; s2 += v * v;
            }
            #pragma unroll
            for (int d = 1; d < 32; d <<= 1) {
                s1 += __shfl_xor(s1, d);
                s2 += __shfl_xor(s2, d);
            }
            if (c31 == 0) {
                int r = 4 * half + (q & 3) + 8 * (q >> 2);
                stats[(w * 32 + r) * 2]     = s1;
                stats[(w * 32 + r) * 2 + 1] = s2;
            }
        }
        __syncthreads();                 // stats in; A(g+1) fully staged

        if (t < 32) {
            float s1 = 0.f, s2 = 0.f;
            #pragma unroll
            for (int wi = 0; wi < 8; ++wi) {
                s1 += stats[(wi * 32 + t) * 2];
                s2 += stats[(wi * 32 + t) * 2 + 1];
            }
            float mean = s1 * (1.0f / OUTF);
            float var  = s2 * (1.0f / OUTF) - mean * mean;
            rowstat[t * 2]     = mean;
            rowstat[t * 2 + 1] = rsqrtf(var + 1e-5f);
        }
        __syncthreads();                 // rowstat ready

        // ---- epilogue: direct frag stores, nt loads/stores (bypass L2);
        //      every instr covers 2 full 128B lines; no trailing barrier ----
        const int m0 = m_base + g * BM;
        const int rbase = 4 * half;
        #pragma unroll
        for (int q = 0; q < 16; ++q) {
            const int r = rbase + (q & 3) + 8 * (q >> 2);
            const float mean = rowstat[r * 2];
            const float rstd = rowstat[r * 2 + 1];
            const size_t off0 = (size_t)(m0 + r) * OUTF + w * 256 + c31;
            #pragma unroll
            for (int ni = 0; ni < 8; ++ni) {
                size_t off = off0 + ni * 32;
                float yv = __builtin_nontemporal_load(y + off);
                float zn = (acc[ni][q] - mean) * rstd;
                __builtin_nontemporal_store((zn + yv) * yv, out + off);
            }
        }
    }
}

extern "C" void kernel_launch(void* const* d_in, const int* in_sizes, int n_in,
                              void* d_out, int out_size, void* d_ws, size_t ws_size,
                              hipStream_t stream) {
    const float* x = (const float*)d_in[0];
    const float* y = (const float*)d_in[1];
    const float* W = (const float*)d_in[2];
    const float* B = (const float*)d_in[3];
    float* out = (float*)d_out;

    if (ws_size >= (size_t)WB_BYTES) {
        unsigned short* Wb = (unsigned short*)d_ws;
        conv_w_kernel<<<512, 256, 0, stream>>>(W, Wb);
        fused_kernel<true><<<NBLK, THREADS, 0, stream>>>(x, y, W, B, Wb, out);
    } else {
        fused_kernel<false><<<NBLK, THREADS, 0, stream>>>(x, y, W, B, nullptr, out);
    }
}